// Round 5
// baseline (240.153 us; speedup 1.0000x reference)
//
#include <hip/hip_runtime.h>
#include <hip/hip_bf16.h>

// ContrastiveLoss: loss = mean_i [ logsumexp_j(logits[i,:]) - pos_sim[i,i] ]
// logits = [20*xn@tn^T | 20*xn@hn^T + I], rows normalized.
// Round 5: NON-scaled fp8 MFMA (mfma_f32_16x16x32_fp8_fp8).
//  - rounds 2 & 4 showed scaled-MFMA keeps C/D in VGPRs (VGPR=252/256,
//    occupancy ~10%); plain MFMA accumulates in AGPRs (round 1: VGPR 76)
//  - fp8 still halves staging bytes / LDS traffic / FETCH vs bf16
//  - BK=64 fp8-bytes: 16 K-iters, 32 MFMAs per barrier-pair (2x round 1's
//    amortization), 16 KB staged/step, frags via ds_read_b64
//  - m97-style single-buffered 2-barrier K-loop (explicit dbuf regressed, R3)
//  - no LDS swizzle: SQ_LDS_BANK_CONFLICT was exactly 4x(read count) in all
//    rounds regardless of swizzle -> structural multi-phase cost, not aliasing

#define AS1 __attribute__((address_space(1)))
#define AS3 __attribute__((address_space(3)))

constexpr int N = 4096;
constexpr int D = 1024;            // elements per row == bytes per fp8 row
constexpr float TEMP_INV = 20.0f;  // 1/0.05
constexpr float CBIAS = 21.0f;     // >= max possible logit (20*1 + 1)

typedef float f32x4 __attribute__((ext_vector_type(4)));

// 3072 blocks x 256. One row per wave (4 rows/block); lane holds 16 floats.
// Blocks 0..15 also zero rowsum so gemm's atomics start clean.
__global__ __launch_bounds__(256) void normalize_kernel(
    const float* __restrict__ in0, const float* __restrict__ in1,
    const float* __restrict__ in2, unsigned int* __restrict__ Abuf,
    unsigned int* __restrict__ Bbuf, float* __restrict__ rowsum) {
    const int t = threadIdx.x, lane = t & 63, wave = t >> 6;
    if (blockIdx.x < 16) rowsum[blockIdx.x * 256 + t] = 0.f;
    const int row = blockIdx.x * 4 + wave;  // 0..12287
    const int mat = row >> 12, r = row & (N - 1);
    const float* src = (mat == 0) ? in0 : (mat == 1) ? in1 : in2;
    unsigned int* dst = (mat == 0) ? (Abuf + (size_t)r * (D / 4))
                      : (mat == 1) ? (Bbuf + (size_t)r * (D / 4))
                                   : (Bbuf + (size_t)(r + N) * (D / 4));
    const float4* s4 = (const float4*)(src + (size_t)r * D);
    float4 v[4];
    float p = 0.f;
#pragma unroll
    for (int j = 0; j < 4; ++j) {
        v[j] = s4[lane + 64 * j];
        p += v[j].x * v[j].x + v[j].y * v[j].y + v[j].z * v[j].z + v[j].w * v[j].w;
    }
#pragma unroll
    for (int m = 1; m < 64; m <<= 1) p += __shfl_xor(p, m);
    const float inv = 1.0f / fmaxf(sqrtf(p), 1e-8f);
#pragma unroll
    for (int j = 0; j < 4; ++j) {
        unsigned int pk = __builtin_amdgcn_cvt_pk_fp8_f32(v[j].x * inv, v[j].y * inv, 0, false);
        pk = __builtin_amdgcn_cvt_pk_fp8_f32(v[j].z * inv, v[j].w * inv, pk, true);
        dst[lane + 64 * j] = pk;
    }
}

// 128x128 tile, BK=64 fp8-bytes, 4 waves 2x2, wave 64x64 via 4x4 of
// 16x16x32 fp8 MFMA, two K-substeps per staged tile.
// A:[N,D] fp8, B:[2N,D] fp8, row-major.
// A-frag (16x16x32 fp8, 2 VGPRs = 8 bytes): row = lane&15, k = (lane>>4)*8+j.
// C/D: col = lane&15, row = (lane>>4)*4 + reg (m89-verified).
__global__ __launch_bounds__(256) void gemm_lse_kernel(
    const unsigned char* __restrict__ A, const unsigned char* __restrict__ B,
    float* __restrict__ rowsum, float* __restrict__ posdiag) {
    __shared__ __align__(16) char As[128 * 64];  // 8 KiB
    __shared__ __align__(16) char Bs[128 * 64];  // 8 KiB

    const int tid = threadIdx.x;
    const int lane = tid & 63;
    const int wave = tid >> 6;
    const int wr = wave >> 1, wc = wave & 1;
    const int quad = lane >> 4, colid = lane & 15;
    const int rowBase = blockIdx.y * 128;
    const int colBase = blockIdx.x * 128;

    f32x4 acc[4][4];
#pragma unroll
    for (int i = 0; i < 4; ++i)
#pragma unroll
        for (int j = 0; j < 4; ++j) acc[i][j] = {0.f, 0.f, 0.f, 0.f};

    // Staging: 512 16B-chunks per 128x64B tile; thread t fills chunks t and
    // t+256 for each matrix. chunk c -> row c>>2, 16B-col c&3, LDS byte c*16.
    const int r0 = tid >> 2, c0 = tid & 3;
    const unsigned char* gA0 = A + (size_t)(rowBase + r0) * D + c0 * 16;
    const unsigned char* gA1 = A + (size_t)(rowBase + r0 + 64) * D + c0 * 16;
    const unsigned char* gB0 = B + (size_t)(colBase + r0) * D + c0 * 16;
    const unsigned char* gB1 = B + (size_t)(colBase + r0 + 64) * D + c0 * 16;

    // Loop-invariant frag byte offsets: frag(row R, ksub) = 8B at
    // R*64 + ksub*32 + quad*8.
    int aoff[4], boff[4];
#pragma unroll
    for (int rt = 0; rt < 4; ++rt)
        aoff[rt] = (wr * 64 + rt * 16 + colid) * 64 + quad * 8;
#pragma unroll
    for (int ct = 0; ct < 4; ++ct)
        boff[ct] = (wc * 64 + ct * 16 + colid) * 64 + quad * 8;

    for (int kb = 0; kb < D / 64; ++kb) {
        const int k0 = kb * 64;
        __syncthreads();  // prior reads done before overwrite
        __builtin_amdgcn_global_load_lds((const AS1 void*)(gA0 + k0),
            (AS3 void*)(As + wave * 1024), 16, 0, 0);
        __builtin_amdgcn_global_load_lds((const AS1 void*)(gA1 + k0),
            (AS3 void*)(As + 4096 + wave * 1024), 16, 0, 0);
        __builtin_amdgcn_global_load_lds((const AS1 void*)(gB0 + k0),
            (AS3 void*)(Bs + wave * 1024), 16, 0, 0);
        __builtin_amdgcn_global_load_lds((const AS1 void*)(gB1 + k0),
            (AS3 void*)(Bs + 4096 + wave * 1024), 16, 0, 0);
        __syncthreads();  // staged data visible

#pragma unroll
        for (int ks = 0; ks < 2; ++ks) {
            long long a[4], b[4];
#pragma unroll
            for (int rt = 0; rt < 4; ++rt)
                a[rt] = *(const long long*)(As + aoff[rt] + ks * 32);
#pragma unroll
            for (int ct = 0; ct < 4; ++ct)
                b[ct] = *(const long long*)(Bs + boff[ct] + ks * 32);
#pragma unroll
            for (int rt = 0; rt < 4; ++rt)
#pragma unroll
                for (int ct = 0; ct < 4; ++ct)
                    acc[rt][ct] = __builtin_amdgcn_mfma_f32_16x16x32_fp8_fp8(
                        a[rt], b[ct], acc[rt][ct], 0, 0, 0);
        }
    }

    // Epilogue: C map col = lane&15, row = quad*4 + reg.
#pragma unroll
    for (int rt = 0; rt < 4; ++rt) {
        float rsum[4] = {0.f, 0.f, 0.f, 0.f};
#pragma unroll
        for (int ct = 0; ct < 4; ++ct) {
#pragma unroll
            for (int reg = 0; reg < 4; ++reg) {
                const int grow = rowBase + wr * 64 + rt * 16 + quad * 4 + reg;
                const int gcol = colBase + wc * 64 + ct * 16 + colid;
                float logit = acc[rt][ct][reg] * TEMP_INV;
                if (gcol == grow + N) logit += 1.0f;      // hard-negative weight
                if (gcol == grow) posdiag[grow] = logit;  // unique writer
                rsum[reg] += __expf(logit - CBIAS);
            }
        }
#pragma unroll
        for (int reg = 0; reg < 4; ++reg) {
            float v = rsum[reg];
            v += __shfl_xor(v, 1);
            v += __shfl_xor(v, 2);
            v += __shfl_xor(v, 4);
            v += __shfl_xor(v, 8);
            if (colid == 0) {
                const int grow = rowBase + wr * 64 + rt * 16 + quad * 4 + reg;
                atomicAdd(&rowsum[grow], v);
            }
        }
    }
}

__global__ __launch_bounds__(256) void finalize_kernel(
    const float* __restrict__ rowsum, const float* __restrict__ posdiag,
    float* __restrict__ out) {
    const int t = threadIdx.x;
    float s = 0.f;
    for (int i = t; i < N; i += 256)
        s += CBIAS + logf(rowsum[i]) - posdiag[i];
    for (int m = 32; m; m >>= 1) s += __shfl_down(s, m);
    __shared__ float red[4];
    const int lane = t & 63, wave = t >> 6;
    if (lane == 0) red[wave] = s;
    __syncthreads();
    if (t == 0) out[0] = (red[0] + red[1] + red[2] + red[3]) / (float)N;
}

extern "C" void kernel_launch(void* const* d_in, const int* in_sizes, int n_in,
                              void* d_out, int out_size, void* d_ws, size_t ws_size,
                              hipStream_t stream) {
    const float* in0 = (const float*)d_in[0];  // input   [N, D] fp32
    const float* in1 = (const float*)d_in[1];  // target  [N, D] fp32
    const float* in2 = (const float*)d_in[2];  // hardneg [N, D] fp32

    // Workspace: Abuf N*D fp8 (4 MiB) | Bbuf 2N*D fp8 (8 MiB) | rowsum | posdiag
    unsigned char* Abuf = (unsigned char*)d_ws;
    unsigned char* Bbuf = Abuf + (size_t)N * D;
    float* rowsum = (float*)(Bbuf + (size_t)2 * N * D);
    float* posdiag = rowsum + N;

    normalize_kernel<<<3 * N / 4, 256, 0, stream>>>(
        in0, in1, in2, (unsigned int*)Abuf, (unsigned int*)Bbuf, rowsum);
    gemm_lse_kernel<<<dim3(2 * N / 128, N / 128), 256, 0, stream>>>(
        Abuf, Bbuf, rowsum, posdiag);
    finalize_kernel<<<1, 256, 0, stream>>>(rowsum, posdiag, (float*)d_out);
}

// Round 6
// 170.461 us; speedup vs baseline: 1.4088x; 1.4088x over previous
//
#include <hip/hip_runtime.h>
#include <hip/hip_bf16.h>

// ContrastiveLoss: loss = mean_i [ logsumexp_j(logits[i,:]) - pos_sim[i,i] ]
// logits = [20*xn@tn^T | 20*xn@hn^T + I], rows normalized.
// Round 6: fp8 MFMA (AGPR acc, VGPR 76 in R5) + PERMUTED row layout so frag
// reads are ds_read_b128 (4 conflict-cyc/read) instead of R5's b64 pattern
// (~28 conflict-cyc/read, 58.7M total -> LDS-pipe-bound, MfmaUtil 16%).
//  - Abuf/Bbuf rows stored with each 64B K-block permuted:
//      perm = q*16 + s*8 + j   <-  orig = s*32 + q*8 + j
//    so one b128 at R*64 + quad*16 carries BOTH 16x16x32 K-substeps
//    (lo 8B = ks0, hi 8B = ks1) in the HW-verified fp8 A/B fragment layout.
//  - 8 b128 frag reads /wave /BK=64 (R1: 16, R5: 16 conflicted b64)
//  - m97-style single-buffered 2-barrier K-loop, 16 iters, 32 MFMA/iter/wave

#define AS1 __attribute__((address_space(1)))
#define AS3 __attribute__((address_space(3)))

constexpr int N = 4096;
constexpr int D = 1024;            // elements per row == bytes per fp8 row
constexpr float TEMP_INV = 20.0f;  // 1/0.05
constexpr float CBIAS = 21.0f;     // >= max possible logit (20*1 + 1)

typedef float f32x4 __attribute__((ext_vector_type(4)));
typedef long long ll2 __attribute__((ext_vector_type(2)));

// 3072 blocks x 256. One row per wave; lane holds 16 CONTIGUOUS floats
// (16L..16L+16) so its 16 fp8 bytes form two 8B groups of the permuted
// layout: lane writes uint2 at perm offsets p8 and p8+16 within block L>>2.
// Blocks 0..15 also zero rowsum so gemm's atomics start clean.
__global__ __launch_bounds__(256) void normalize_kernel(
    const float* __restrict__ in0, const float* __restrict__ in1,
    const float* __restrict__ in2, unsigned char* __restrict__ Abuf,
    unsigned char* __restrict__ Bbuf, float* __restrict__ rowsum) {
    const int t = threadIdx.x, lane = t & 63, wave = t >> 6;
    if (blockIdx.x < 16) rowsum[blockIdx.x * 256 + t] = 0.f;
    const int row = blockIdx.x * 4 + wave;  // 0..12287
    const int mat = row >> 12, r = row & (N - 1);
    const float* src = (mat == 0) ? in0 : (mat == 1) ? in1 : in2;
    unsigned char* dst = (mat == 0) ? (Abuf + (size_t)r * D)
                       : (mat == 1) ? (Bbuf + (size_t)r * D)
                                    : (Bbuf + (size_t)(r + N) * D);
    const float4* s4 = (const float4*)(src + (size_t)r * D);
    float4 v[4];
    float p = 0.f;
#pragma unroll
    for (int j = 0; j < 4; ++j) {
        v[j] = s4[4 * lane + j];  // floats 16*lane .. 16*lane+16
        p += v[j].x * v[j].x + v[j].y * v[j].y + v[j].z * v[j].z + v[j].w * v[j].w;
    }
#pragma unroll
    for (int m = 1; m < 64; m <<= 1) p += __shfl_xor(p, m);
    const float inv = 1.0f / fmaxf(sqrtf(p), 1e-8f);
    unsigned int w[4];
#pragma unroll
    for (int j = 0; j < 4; ++j) {
        w[j] = __builtin_amdgcn_cvt_pk_fp8_f32(v[j].x * inv, v[j].y * inv, 0, false);
        w[j] = __builtin_amdgcn_cvt_pk_fp8_f32(v[j].z * inv, v[j].w * inv, w[j], true);
    }
    // orig groups: (s,q) with s=bit1(lo2') mapping: lo2=lane&3
    //   lo2=0: (0,q0)->p 0,(0,q1)->16 ; lo2=1: (0,q2)->32,(0,q3)->48
    //   lo2=2: (1,q0)->8,(1,q1)->24   ; lo2=3: (1,q2)->40,(1,q3)->56
    const int lo2 = lane & 3;
    const int p8 = (lo2 & 1) * 32 + (lo2 >> 1) * 8;
    unsigned char* bp = dst + (lane >> 2) * 64;
    uint2 g0 = {w[0], w[1]}, g1 = {w[2], w[3]};
    *(uint2*)(bp + p8) = g0;
    *(uint2*)(bp + p8 + 16) = g1;
}

// 128x128 tile, BK=64 fp8-bytes, 4 waves 2x2, wave 64x64 via 4x4 of
// 16x16x32 fp8 MFMA, two K-substeps per staged tile, one b128/frag-pair.
// A:[N,D] fp8 permuted, B:[2N,D] fp8 permuted, row-major.
// C/D: col = lane&15, row = (lane>>4)*4 + reg (m89-verified).
__global__ __launch_bounds__(256) void gemm_lse_kernel(
    const unsigned char* __restrict__ A, const unsigned char* __restrict__ B,
    float* __restrict__ rowsum, float* __restrict__ posdiag) {
    __shared__ __align__(16) char As[128 * 64];  // 8 KiB
    __shared__ __align__(16) char Bs[128 * 64];  // 8 KiB

    const int tid = threadIdx.x;
    const int lane = tid & 63;
    const int wave = tid >> 6;
    const int wr = wave >> 1, wc = wave & 1;
    const int quad = lane >> 4, colid = lane & 15;
    const int rowBase = blockIdx.y * 128;
    const int colBase = blockIdx.x * 128;

    f32x4 acc[4][4];
#pragma unroll
    for (int i = 0; i < 4; ++i)
#pragma unroll
        for (int j = 0; j < 4; ++j) acc[i][j] = {0.f, 0.f, 0.f, 0.f};

    // Staging (unchanged from R5, which passed): thread t fills 16B chunks
    // t and t+256; chunk c -> row c>>2, 16B-col c&3 (permuted space).
    const int r0 = tid >> 2, c0 = tid & 3;
    const unsigned char* gA0 = A + (size_t)(rowBase + r0) * D + c0 * 16;
    const unsigned char* gA1 = A + (size_t)(rowBase + r0 + 64) * D + c0 * 16;
    const unsigned char* gB0 = B + (size_t)(colBase + r0) * D + c0 * 16;
    const unsigned char* gB1 = B + (size_t)(colBase + r0 + 64) * D + c0 * 16;

    // Frag offsets: one b128 per (tile,row): lo 8B = ks0, hi 8B = ks1.
    int aoff[4], boff[4];
#pragma unroll
    for (int rt = 0; rt < 4; ++rt)
        aoff[rt] = (wr * 64 + rt * 16 + colid) * 64 + quad * 16;
#pragma unroll
    for (int ct = 0; ct < 4; ++ct)
        boff[ct] = (wc * 64 + ct * 16 + colid) * 64 + quad * 16;

    for (int kb = 0; kb < D / 64; ++kb) {
        const int k0 = kb * 64;
        __syncthreads();  // prior reads done before overwrite
        __builtin_amdgcn_global_load_lds((const AS1 void*)(gA0 + k0),
            (AS3 void*)(As + wave * 1024), 16, 0, 0);
        __builtin_amdgcn_global_load_lds((const AS1 void*)(gA1 + k0),
            (AS3 void*)(As + 4096 + wave * 1024), 16, 0, 0);
        __builtin_amdgcn_global_load_lds((const AS1 void*)(gB0 + k0),
            (AS3 void*)(Bs + wave * 1024), 16, 0, 0);
        __builtin_amdgcn_global_load_lds((const AS1 void*)(gB1 + k0),
            (AS3 void*)(Bs + 4096 + wave * 1024), 16, 0, 0);
        __syncthreads();  // staged data visible

        ll2 a[4], b[4];
#pragma unroll
        for (int rt = 0; rt < 4; ++rt)
            a[rt] = *(const ll2*)(As + aoff[rt]);
#pragma unroll
        for (int ct = 0; ct < 4; ++ct)
            b[ct] = *(const ll2*)(Bs + boff[ct]);
#pragma unroll
        for (int ks = 0; ks < 2; ++ks)
#pragma unroll
            for (int rt = 0; rt < 4; ++rt)
#pragma unroll
                for (int ct = 0; ct < 4; ++ct)
                    acc[rt][ct] = __builtin_amdgcn_mfma_f32_16x16x32_fp8_fp8(
                        a[rt][ks], b[ct][ks], acc[rt][ct], 0, 0, 0);
    }

    // Epilogue: C map col = lane&15, row = quad*4 + reg.
#pragma unroll
    for (int rt = 0; rt < 4; ++rt) {
        float rsum[4] = {0.f, 0.f, 0.f, 0.f};
#pragma unroll
        for (int ct = 0; ct < 4; ++ct) {
#pragma unroll
            for (int reg = 0; reg < 4; ++reg) {
                const int grow = rowBase + wr * 64 + rt * 16 + quad * 4 + reg;
                const int gcol = colBase + wc * 64 + ct * 16 + colid;
                float logit = acc[rt][ct][reg] * TEMP_INV;
                if (gcol == grow + N) logit += 1.0f;      // hard-negative weight
                if (gcol == grow) posdiag[grow] = logit;  // unique writer
                rsum[reg] += __expf(logit - CBIAS);
            }
        }
#pragma unroll
        for (int reg = 0; reg < 4; ++reg) {
            float v = rsum[reg];
            v += __shfl_xor(v, 1);
            v += __shfl_xor(v, 2);
            v += __shfl_xor(v, 4);
            v += __shfl_xor(v, 8);
            if (colid == 0) {
                const int grow = rowBase + wr * 64 + rt * 16 + quad * 4 + reg;
                atomicAdd(&rowsum[grow], v);
            }
        }
    }
}

__global__ __launch_bounds__(256) void finalize_kernel(
    const float* __restrict__ rowsum, const float* __restrict__ posdiag,
    float* __restrict__ out) {
    const int t = threadIdx.x;
    float s = 0.f;
    for (int i = t; i < N; i += 256)
        s += CBIAS + logf(rowsum[i]) - posdiag[i];
    for (int m = 32; m; m >>= 1) s += __shfl_down(s, m);
    __shared__ float red[4];
    const int lane = t & 63, wave = t >> 6;
    if (lane == 0) red[wave] = s;
    __syncthreads();
    if (t == 0) out[0] = (red[0] + red[1] + red[2] + red[3]) / (float)N;
}

extern "C" void kernel_launch(void* const* d_in, const int* in_sizes, int n_in,
                              void* d_out, int out_size, void* d_ws, size_t ws_size,
                              hipStream_t stream) {
    const float* in0 = (const float*)d_in[0];  // input   [N, D] fp32
    const float* in1 = (const float*)d_in[1];  // target  [N, D] fp32
    const float* in2 = (const float*)d_in[2];  // hardneg [N, D] fp32

    // Workspace: Abuf N*D fp8 (4 MiB) | Bbuf 2N*D fp8 (8 MiB) | rowsum | posdiag
    unsigned char* Abuf = (unsigned char*)d_ws;
    unsigned char* Bbuf = Abuf + (size_t)N * D;
    float* rowsum = (float*)(Bbuf + (size_t)2 * N * D);
    float* posdiag = rowsum + N;

    normalize_kernel<<<3 * N / 4, 256, 0, stream>>>(in0, in1, in2, Abuf, Bbuf,
                                                    rowsum);
    gemm_lse_kernel<<<dim3(2 * N / 128, N / 128), 256, 0, stream>>>(
        Abuf, Bbuf, rowsum, posdiag);
    finalize_kernel<<<1, 256, 0, stream>>>(rowsum, posdiag, (float*)d_out);
}

// Round 7
// 161.786 us; speedup vs baseline: 1.4844x; 1.0536x over previous
//
#include <hip/hip_runtime.h>
#include <hip/hip_bf16.h>

// ContrastiveLoss: loss = mean_i [ logsumexp_j(logits[i,:]) - pos_sim[i,i] ]
// logits = [20*xn@tn^T | 20*xn@hn^T + I], rows normalized.
// Round 7: R6 structure (fp8 MFMA, AGPR acc, permuted 64B K-blocks so frag
// reads are single b128) with BK=128: 8 K-iters instead of 16 -> half the
// barrier/vmcnt(0) drains, 64 MFMA per wave per drain.
//  - At row-stride 128B an unswizzled b128 frag read puts all 16 lanes of a
//    quad on the same 4 banks (R5's 16-way disaster), so chunk-XOR swizzle
//    phys = logical ^ (R&7) is now load-bearing: staging source side AND
//    frag offsets; 16 lanes spread over 8 chunk positions -> 2-way (free).
//  - R6 evidence: 4 conflict-cyc per b128 is the structural floor; b64 frag
//    reads cost ~28 -> keep everything b128.
//  - scaled-MFMA banned (R2/R4: C/D stays in VGPRs, 252+ regs, 10% occ).

#define AS1 __attribute__((address_space(1)))
#define AS3 __attribute__((address_space(3)))

constexpr int N = 4096;
constexpr int D = 1024;            // elements per row == bytes per fp8 row
constexpr float TEMP_INV = 20.0f;  // 1/0.05
constexpr float CBIAS = 21.0f;     // >= max possible logit (20*1 + 1)

typedef float f32x4 __attribute__((ext_vector_type(4)));
typedef long long ll2 __attribute__((ext_vector_type(2)));

// 3072 blocks x 256. One row per wave; lane holds 16 CONTIGUOUS floats
// (16L..16L+16) -> two 8B groups of the permuted layout
// (perm = q*16 + s*8 + j  <-  orig = s*32 + q*8 + j, per 64B K-block).
// Blocks 0..15 also zero rowsum so gemm's atomics start clean.
__global__ __launch_bounds__(256) void normalize_kernel(
    const float* __restrict__ in0, const float* __restrict__ in1,
    const float* __restrict__ in2, unsigned char* __restrict__ Abuf,
    unsigned char* __restrict__ Bbuf, float* __restrict__ rowsum) {
    const int t = threadIdx.x, lane = t & 63, wave = t >> 6;
    if (blockIdx.x < 16) rowsum[blockIdx.x * 256 + t] = 0.f;
    const int row = blockIdx.x * 4 + wave;  // 0..12287
    const int mat = row >> 12, r = row & (N - 1);
    const float* src = (mat == 0) ? in0 : (mat == 1) ? in1 : in2;
    unsigned char* dst = (mat == 0) ? (Abuf + (size_t)r * D)
                       : (mat == 1) ? (Bbuf + (size_t)r * D)
                                    : (Bbuf + (size_t)(r + N) * D);
    const float4* s4 = (const float4*)(src + (size_t)r * D);
    float4 v[4];
    float p = 0.f;
#pragma unroll
    for (int j = 0; j < 4; ++j) {
        v[j] = s4[4 * lane + j];  // floats 16*lane .. 16*lane+16
        p += v[j].x * v[j].x + v[j].y * v[j].y + v[j].z * v[j].z + v[j].w * v[j].w;
    }
#pragma unroll
    for (int m = 1; m < 64; m <<= 1) p += __shfl_xor(p, m);
    const float inv = 1.0f / fmaxf(sqrtf(p), 1e-8f);
    unsigned int w[4];
#pragma unroll
    for (int j = 0; j < 4; ++j) {
        w[j] = __builtin_amdgcn_cvt_pk_fp8_f32(v[j].x * inv, v[j].y * inv, 0, false);
        w[j] = __builtin_amdgcn_cvt_pk_fp8_f32(v[j].z * inv, v[j].w * inv, w[j], true);
    }
    const int lo2 = lane & 3;
    const int p8 = (lo2 & 1) * 32 + (lo2 >> 1) * 8;
    unsigned char* bp = dst + (lane >> 2) * 64;
    uint2 g0 = {w[0], w[1]}, g1 = {w[2], w[3]};
    *(uint2*)(bp + p8) = g0;
    *(uint2*)(bp + p8 + 16) = g1;
}

// 128x128 tile, BK=128 fp8-bytes, 4 waves 2x2, wave 64x64 via 4x4 of
// 16x16x32 fp8 MFMA, 4 K-substeps per staged tile, b128 frag reads.
// A:[N,D] fp8 permuted, B:[2N,D] fp8 permuted, row-major.
// C/D: col = lane&15, row = (lane>>4)*4 + reg (m89-verified).
__global__ __launch_bounds__(256) void gemm_lse_kernel(
    const unsigned char* __restrict__ A, const unsigned char* __restrict__ B,
    float* __restrict__ rowsum, float* __restrict__ posdiag) {
    __shared__ __align__(16) char As[128 * 128];  // 16 KiB
    __shared__ __align__(16) char Bs[128 * 128];  // 16 KiB

    const int tid = threadIdx.x;
    const int lane = tid & 63;
    const int wave = tid >> 6;
    const int wr = wave >> 1, wc = wave & 1;
    const int quad = lane >> 4, colid = lane & 15;
    const int rowBase = blockIdx.y * 128;
    const int colBase = blockIdx.x * 128;

    f32x4 acc[4][4];
#pragma unroll
    for (int i = 0; i < 4; ++i)
#pragma unroll
        for (int j = 0; j < 4; ++j) acc[i][j] = {0.f, 0.f, 0.f, 0.f};

    // Staging: 1024 16B phys-chunks per 128x128B tile; thread t fills chunks
    // t+256j (LDS byte (t+256j)*16), j=0..3. phys chunk c -> row c>>3,
    // within-row phys col c&7; global source logical col = (c&7) ^ (row&7)
    // (self-inverse XOR; row&7 = (t>>3)&7 is j-invariant).
    const int srow = tid >> 3;                      // 0..31
    const int scol = (tid & 7) ^ ((tid >> 3) & 7);  // 16B units
    const unsigned char* gA[4];
    const unsigned char* gB[4];
#pragma unroll
    for (int j = 0; j < 4; ++j) {
        gA[j] = A + (size_t)(rowBase + srow + 32 * j) * D + scol * 16;
        gB[j] = B + (size_t)(colBase + srow + 32 * j) * D + scol * 16;
    }

    // Frag offsets: for K-half h (64 K-elems), row R: logical chunk h*4+quad,
    // phys = logical ^ (R&7). b128 lo 8B = ks0, hi 8B = ks1 (permuted blocks).
    int aoff[4][2], boff[4][2];
#pragma unroll
    for (int rt = 0; rt < 4; ++rt) {
        const int R = wr * 64 + rt * 16 + colid;
#pragma unroll
        for (int h = 0; h < 2; ++h)
            aoff[rt][h] = R * 128 + ((h * 4 + quad) ^ (R & 7)) * 16;
    }
#pragma unroll
    for (int ct = 0; ct < 4; ++ct) {
        const int C = wc * 64 + ct * 16 + colid;
#pragma unroll
        for (int h = 0; h < 2; ++h)
            boff[ct][h] = C * 128 + ((h * 4 + quad) ^ (C & 7)) * 16;
    }

    for (int kb = 0; kb < D / 128; ++kb) {
        const int k0 = kb * 128;
        __syncthreads();  // prior reads done before overwrite
#pragma unroll
        for (int j = 0; j < 4; ++j) {
            __builtin_amdgcn_global_load_lds((const AS1 void*)(gA[j] + k0),
                (AS3 void*)(As + (tid + 256 * j) * 16), 16, 0, 0);
            __builtin_amdgcn_global_load_lds((const AS1 void*)(gB[j] + k0),
                (AS3 void*)(Bs + (tid + 256 * j) * 16), 16, 0, 0);
        }
        __syncthreads();  // staged data visible

#pragma unroll
        for (int h = 0; h < 2; ++h) {
            ll2 a[4], b[4];
#pragma unroll
            for (int rt = 0; rt < 4; ++rt)
                a[rt] = *(const ll2*)(As + aoff[rt][h]);
#pragma unroll
            for (int ct = 0; ct < 4; ++ct)
                b[ct] = *(const ll2*)(Bs + boff[ct][h]);
#pragma unroll
            for (int ks = 0; ks < 2; ++ks)
#pragma unroll
                for (int rt = 0; rt < 4; ++rt)
#pragma unroll
                    for (int ct = 0; ct < 4; ++ct)
                        acc[rt][ct] = __builtin_amdgcn_mfma_f32_16x16x32_fp8_fp8(
                            a[rt][ks], b[ct][ks], acc[rt][ct], 0, 0, 0);
        }
    }

    // Epilogue: C map col = lane&15, row = quad*4 + reg.
#pragma unroll
    for (int rt = 0; rt < 4; ++rt) {
        float rsum[4] = {0.f, 0.f, 0.f, 0.f};
#pragma unroll
        for (int ct = 0; ct < 4; ++ct) {
#pragma unroll
            for (int reg = 0; reg < 4; ++reg) {
                const int grow = rowBase + wr * 64 + rt * 16 + quad * 4 + reg;
                const int gcol = colBase + wc * 64 + ct * 16 + colid;
                float logit = acc[rt][ct][reg] * TEMP_INV;
                if (gcol == grow + N) logit += 1.0f;      // hard-negative weight
                if (gcol == grow) posdiag[grow] = logit;  // unique writer
                rsum[reg] += __expf(logit - CBIAS);
            }
        }
#pragma unroll
        for (int reg = 0; reg < 4; ++reg) {
            float v = rsum[reg];
            v += __shfl_xor(v, 1);
            v += __shfl_xor(v, 2);
            v += __shfl_xor(v, 4);
            v += __shfl_xor(v, 8);
            if (colid == 0) {
                const int grow = rowBase + wr * 64 + rt * 16 + quad * 4 + reg;
                atomicAdd(&rowsum[grow], v);
            }
        }
    }
}

__global__ __launch_bounds__(256) void finalize_kernel(
    const float* __restrict__ rowsum, const float* __restrict__ posdiag,
    float* __restrict__ out) {
    const int t = threadIdx.x;
    float s = 0.f;
    for (int i = t; i < N; i += 256)
        s += CBIAS + logf(rowsum[i]) - posdiag[i];
    for (int m = 32; m; m >>= 1) s += __shfl_down(s, m);
    __shared__ float red[4];
    const int lane = t & 63, wave = t >> 6;
    if (lane == 0) red[wave] = s;
    __syncthreads();
    if (t == 0) out[0] = (red[0] + red[1] + red[2] + red[3]) / (float)N;
}

extern "C" void kernel_launch(void* const* d_in, const int* in_sizes, int n_in,
                              void* d_out, int out_size, void* d_ws, size_t ws_size,
                              hipStream_t stream) {
    const float* in0 = (const float*)d_in[0];  // input   [N, D] fp32
    const float* in1 = (const float*)d_in[1];  // target  [N, D] fp32
    const float* in2 = (const float*)d_in[2];  // hardneg [N, D] fp32

    // Workspace: Abuf N*D fp8 (4 MiB) | Bbuf 2N*D fp8 (8 MiB) | rowsum | posdiag
    unsigned char* Abuf = (unsigned char*)d_ws;
    unsigned char* Bbuf = Abuf + (size_t)N * D;
    float* rowsum = (float*)(Bbuf + (size_t)2 * N * D);
    float* posdiag = rowsum + N;

    normalize_kernel<<<3 * N / 4, 256, 0, stream>>>(in0, in1, in2, Abuf, Bbuf,
                                                    rowsum);
    gemm_lse_kernel<<<dim3(2 * N / 128, N / 128), 256, 0, stream>>>(
        Abuf, Bbuf, rowsum, posdiag);
    finalize_kernel<<<1, 256, 0, stream>>>(rowsum, posdiag, (float*)d_out);
}

// Round 8
// 159.778 us; speedup vs baseline: 1.5030x; 1.0126x over previous
//
#include <hip/hip_runtime.h>
#include <hip/hip_bf16.h>

// ContrastiveLoss: loss = mean_i [ logsumexp_j(logits[i,:]) - pos_sim[i,i] ]
// logits = [20*xn@tn^T | 20*xn@hn^T + I], rows normalized.
// Round 8: i8 MFMA (mfma_i32_16x16x64_i8, plain MFMA -> AGPR acc) at 2x the
// fp8 FLOP rate; K=64/inst so the lane fragment is 16 CONTIGUOUS bytes ->
// same 16B-chunk geometry as R7 (chunk = h*4+quad, XOR-swizzled, 0 conflicts
// measured) with NO row permutation. Normalize emits int8 (round(127*xn)).
//  - R7 budget: MFMA ~2500 cyc/CU-iter == LDS ~2560 -> halving MFMA via i8
//    moves the floor to the LDS pipe.
//  - scaled-MFMA banned (R2/R4: C/D stays in VGPRs, 252+ regs, 10% occ).
//  - b64 LDS reads banned (R5: ~28 conflict-cyc each); everything b128.
//  - logit = acc * (20/127^2); diag cancellation makes i8 loss error ~1e-3.

#define AS1 __attribute__((address_space(1)))
#define AS3 __attribute__((address_space(3)))

constexpr int N = 4096;
constexpr int D = 1024;            // elements per row == bytes per i8 row
constexpr float QSCALE = 127.0f;
constexpr float LSCALE = 20.0f / (127.0f * 127.0f);  // acc -> logit
constexpr float CBIAS = 21.0f;     // >= max possible logit (20*1 + 1)

typedef int i32x4 __attribute__((ext_vector_type(4)));

// 3072 blocks x 256. One row per wave; lane holds 16 CONTIGUOUS floats ->
// 16 int8 bytes -> one uint4 store at byte 16*lane (wave writes 1KB contig).
// Blocks 0..15 also zero rowsum so gemm's atomics start clean.
__global__ __launch_bounds__(256) void normalize_kernel(
    const float* __restrict__ in0, const float* __restrict__ in1,
    const float* __restrict__ in2, unsigned char* __restrict__ Abuf,
    unsigned char* __restrict__ Bbuf, float* __restrict__ rowsum) {
    const int t = threadIdx.x, lane = t & 63, wave = t >> 6;
    if (blockIdx.x < 16) rowsum[blockIdx.x * 256 + t] = 0.f;
    const int row = blockIdx.x * 4 + wave;  // 0..12287
    const int mat = row >> 12, r = row & (N - 1);
    const float* src = (mat == 0) ? in0 : (mat == 1) ? in1 : in2;
    unsigned char* dst = (mat == 0) ? (Abuf + (size_t)r * D)
                       : (mat == 1) ? (Bbuf + (size_t)r * D)
                                    : (Bbuf + (size_t)(r + N) * D);
    const float4* s4 = (const float4*)(src + (size_t)r * D);
    float4 v[4];
    float p = 0.f;
#pragma unroll
    for (int j = 0; j < 4; ++j) {
        v[j] = s4[4 * lane + j];  // floats 16*lane .. 16*lane+15
        p += v[j].x * v[j].x + v[j].y * v[j].y + v[j].z * v[j].z + v[j].w * v[j].w;
    }
#pragma unroll
    for (int m = 1; m < 64; m <<= 1) p += __shfl_xor(p, m);
    const float s = QSCALE / fmaxf(sqrtf(p), 1e-8f);
    uint4 o;
    unsigned int w[4];
#pragma unroll
    for (int j = 0; j < 4; ++j) {
        int q0 = min(127, max(-127, __float2int_rn(v[j].x * s)));
        int q1 = min(127, max(-127, __float2int_rn(v[j].y * s)));
        int q2 = min(127, max(-127, __float2int_rn(v[j].z * s)));
        int q3 = min(127, max(-127, __float2int_rn(v[j].w * s)));
        w[j] = (q0 & 255) | ((q1 & 255) << 8) | ((q2 & 255) << 16)
             | ((unsigned)(q3 & 255) << 24);
    }
    o.x = w[0]; o.y = w[1]; o.z = w[2]; o.w = w[3];
    ((uint4*)dst)[lane] = o;
}

// 128x128 tile, BK=128 i8-bytes, 4 waves 2x2, wave 64x64 via 4x4 of
// 16x16x64 i8 MFMA, 2 K-substeps (h) per staged tile, b128 frag reads.
// A:[N,D] i8, B:[2N,D] i8, row-major (no permute: frag = 16 contig bytes,
// row = lane&15, k = (lane>>4)*16 + j).
// C/D: col = lane&15, row = (lane>>4)*4 + reg (m89-verified, shape-determined).
__global__ __launch_bounds__(256) void gemm_lse_kernel(
    const unsigned char* __restrict__ A, const unsigned char* __restrict__ B,
    float* __restrict__ rowsum, float* __restrict__ posdiag) {
    __shared__ __align__(16) char As[128 * 128];  // 16 KiB
    __shared__ __align__(16) char Bs[128 * 128];  // 16 KiB

    const int tid = threadIdx.x;
    const int lane = tid & 63;
    const int wave = tid >> 6;
    const int wr = wave >> 1, wc = wave & 1;
    const int quad = lane >> 4, colid = lane & 15;
    const int rowBase = blockIdx.y * 128;
    const int colBase = blockIdx.x * 128;

    i32x4 acc[4][4];
#pragma unroll
    for (int i = 0; i < 4; ++i)
#pragma unroll
        for (int j = 0; j < 4; ++j) acc[i][j] = {0, 0, 0, 0};

    // Staging (identical to R7, measured 0 conflicts): 1024 16B phys-chunks
    // per 128x128B tile; thread t fills chunks t+256j. phys chunk c -> row
    // c>>3, phys col c&7; global logical col = (c&7) ^ (row&7).
    const int srow = tid >> 3;                      // 0..31
    const int scol = (tid & 7) ^ ((tid >> 3) & 7);  // 16B units
    const unsigned char* gA[4];
    const unsigned char* gB[4];
#pragma unroll
    for (int j = 0; j < 4; ++j) {
        gA[j] = A + (size_t)(rowBase + srow + 32 * j) * D + scol * 16;
        gB[j] = B + (size_t)(colBase + srow + 32 * j) * D + scol * 16;
    }

    // Frag offsets: K-half h (64 K-elems), row R: logical chunk h*4+quad,
    // phys = logical ^ (R&7). One b128 IS the i8 MFMA operand (i32x4).
    int aoff[4][2], boff[4][2];
#pragma unroll
    for (int rt = 0; rt < 4; ++rt) {
        const int R = wr * 64 + rt * 16 + colid;
#pragma unroll
        for (int h = 0; h < 2; ++h)
            aoff[rt][h] = R * 128 + ((h * 4 + quad) ^ (R & 7)) * 16;
    }
#pragma unroll
    for (int ct = 0; ct < 4; ++ct) {
        const int C = wc * 64 + ct * 16 + colid;
#pragma unroll
        for (int h = 0; h < 2; ++h)
            boff[ct][h] = C * 128 + ((h * 4 + quad) ^ (C & 7)) * 16;
    }

    for (int kb = 0; kb < D / 128; ++kb) {
        const int k0 = kb * 128;
        __syncthreads();  // prior reads done before overwrite
#pragma unroll
        for (int j = 0; j < 4; ++j) {
            __builtin_amdgcn_global_load_lds((const AS1 void*)(gA[j] + k0),
                (AS3 void*)(As + (tid + 256 * j) * 16), 16, 0, 0);
            __builtin_amdgcn_global_load_lds((const AS1 void*)(gB[j] + k0),
                (AS3 void*)(Bs + (tid + 256 * j) * 16), 16, 0, 0);
        }
        __syncthreads();  // staged data visible

#pragma unroll
        for (int h = 0; h < 2; ++h) {
            i32x4 a[4], b[4];
#pragma unroll
            for (int rt = 0; rt < 4; ++rt)
                a[rt] = *(const i32x4*)(As + aoff[rt][h]);
#pragma unroll
            for (int ct = 0; ct < 4; ++ct)
                b[ct] = *(const i32x4*)(Bs + boff[ct][h]);
#pragma unroll
            for (int rt = 0; rt < 4; ++rt)
#pragma unroll
                for (int ct = 0; ct < 4; ++ct)
                    acc[rt][ct] = __builtin_amdgcn_mfma_i32_16x16x64_i8(
                        a[rt], b[ct], acc[rt][ct], 0, 0, 0);
        }
    }

    // Epilogue: C map col = lane&15, row = quad*4 + reg.
#pragma unroll
    for (int rt = 0; rt < 4; ++rt) {
        float rsum[4] = {0.f, 0.f, 0.f, 0.f};
#pragma unroll
        for (int ct = 0; ct < 4; ++ct) {
#pragma unroll
            for (int reg = 0; reg < 4; ++reg) {
                const int grow = rowBase + wr * 64 + rt * 16 + quad * 4 + reg;
                const int gcol = colBase + wc * 64 + ct * 16 + colid;
                float logit = (float)acc[rt][ct][reg] * LSCALE;
                if (gcol == grow + N) logit += 1.0f;      // hard-negative weight
                if (gcol == grow) posdiag[grow] = logit;  // unique writer
                rsum[reg] += __expf(logit - CBIAS);
            }
        }
#pragma unroll
        for (int reg = 0; reg < 4; ++reg) {
            float v = rsum[reg];
            v += __shfl_xor(v, 1);
            v += __shfl_xor(v, 2);
            v += __shfl_xor(v, 4);
            v += __shfl_xor(v, 8);
            if (colid == 0) {
                const int grow = rowBase + wr * 64 + rt * 16 + quad * 4 + reg;
                atomicAdd(&rowsum[grow], v);
            }
        }
    }
}

__global__ __launch_bounds__(256) void finalize_kernel(
    const float* __restrict__ rowsum, const float* __restrict__ posdiag,
    float* __restrict__ out) {
    const int t = threadIdx.x;
    float s = 0.f;
    for (int i = t; i < N; i += 256)
        s += CBIAS + logf(rowsum[i]) - posdiag[i];
    for (int m = 32; m; m >>= 1) s += __shfl_down(s, m);
    __shared__ float red[4];
    const int lane = t & 63, wave = t >> 6;
    if (lane == 0) red[wave] = s;
    __syncthreads();
    if (t == 0) out[0] = (red[0] + red[1] + red[2] + red[3]) / (float)N;
}

extern "C" void kernel_launch(void* const* d_in, const int* in_sizes, int n_in,
                              void* d_out, int out_size, void* d_ws, size_t ws_size,
                              hipStream_t stream) {
    const float* in0 = (const float*)d_in[0];  // input   [N, D] fp32
    const float* in1 = (const float*)d_in[1];  // target  [N, D] fp32
    const float* in2 = (const float*)d_in[2];  // hardneg [N, D] fp32

    // Workspace: Abuf N*D i8 (4 MiB) | Bbuf 2N*D i8 (8 MiB) | rowsum | posdiag
    unsigned char* Abuf = (unsigned char*)d_ws;
    unsigned char* Bbuf = Abuf + (size_t)N * D;
    float* rowsum = (float*)(Bbuf + (size_t)2 * N * D);
    float* posdiag = rowsum + N;

    normalize_kernel<<<3 * N / 4, 256, 0, stream>>>(in0, in1, in2, Abuf, Bbuf,
                                                    rowsum);
    gemm_lse_kernel<<<dim3(2 * N / 128, N / 128), 256, 0, stream>>>(
        Abuf, Bbuf, rowsum, posdiag);
    finalize_kernel<<<1, 256, 0, stream>>>(rowsum, posdiag, (float*)d_out);
}